// Round 7
// baseline (963.084 us; speedup 1.0000x reference)
//
#include <hip/hip_runtime.h>
#include <hip/hip_fp16.h>
#include <math.h>

#define HID   64
#define HEADS 4
#define DH    16
#define NU    30000
#define NE_   60000
#define NV    1000
#define NTOT  91000
#define ETOT  870000
#define NSLOT 541000
#define LAYERS 2

// Edge-type tables
__device__ const int d_EOFF[14] = {0,150000,270000,330000,370000,400000,450000,
                                   570000,630000,670000,700000,750000,810000,870000};
__device__ const int d_ECNT[13] = {150000,120000,60000,40000,30000,50000,
                                   120000,60000,40000,30000,50000,60000,60000};
__device__ const int d_EST[13]  = {0,0,0,0,0,0,1,1,1,1,1,1,2};
__device__ const int d_EDT[13]  = {0,1,1,1,1,1,0,0,0,0,0,2,1};
__device__ const int d_NOFF[3]  = {0, NU, NU + NE_};
// slot base per edge type in the kvt mega-table (src-node indexed per e)
__device__ const int d_EBASE[13] = {0,30000,60000,90000,120000,150000,
                                    180000,240000,300000,360000,420000,480000,540000};
__device__ const int d_ESLOTS[13] = {30000,30000,30000,30000,30000,30000,
                                     60000,60000,60000,60000,60000,60000,1000};
// k_trans 64-slot block offsets per e: 6x469, 6x938, 1x16
__device__ const int d_TBOFF[14] = {0,469,938,1407,1876,2345,2814,
                                    3752,4690,5628,6566,7504,8442,8458};

struct EdgePtrs { const int* p[13]; };

__device__ __forceinline__ int node_type(int n) {
    return (n >= NU) + (n >= NU + NE_);
}

// ---------------- input projection: h = x@W + b + emb[ids] ----------------
__global__ void k_init(const float* __restrict__ xu, const float* __restrict__ xe,
                       const float* __restrict__ xv,
                       const float* __restrict__ Wu, const float* __restrict__ bu,
                       const float* __restrict__ We, const float* __restrict__ be,
                       const float* __restrict__ Wv_, const float* __restrict__ bv,
                       const float* __restrict__ embu, const float* __restrict__ embe,
                       const float* __restrict__ embv,
                       const int* __restrict__ idu, const int* __restrict__ ide,
                       const int* __restrict__ idv,
                       float* __restrict__ h) {
    int gid = blockIdx.x * blockDim.x + threadIdx.x;
    if (gid >= NTOT * HID) return;
    int node = gid >> 6, j = gid & 63;
    const float *x, *W, *b, *emb; const int* ids; int in_dim, n;
    if (node < NU)            { n = node;           x = xu; W = Wu;  b = bu; emb = embu; ids = idu; in_dim = 32; }
    else if (node < NU + NE_) { n = node - NU;      x = xe; W = We;  b = be; emb = embe; ids = ide; in_dim = 32; }
    else                      { n = node - NU - NE_;x = xv; W = Wv_; b = bv; emb = embv; ids = idv; in_dim = 16; }
    float acc = b[j] + emb[(size_t)ids[n] * HID + j];
    for (int i = 0; i < in_dim; i++) acc += x[(size_t)n * in_dim + i] * W[i * HID + j];
    h[gid] = acc;
}

// ---------------- CSR build (exact rows, entry = slot index) ----------------
__global__ void k_cnt(EdgePtrs ep, int* __restrict__ cnt) {
    int eidx = blockIdx.x * blockDim.x + threadIdx.x;
    if (eidx >= ETOT) return;
    int e = 0;
    #pragma unroll
    for (int i = 1; i < 13; i++) e += (eidx >= d_EOFF[i]);
    int li = eidx - d_EOFF[e];
    int dst = ep.p[e][d_ECNT[e] + li];
    atomicAdd(&cnt[d_NOFF[d_EDT[e]] + dst], 1);
}

__global__ void k_scan_a(const int* __restrict__ cnt, int* __restrict__ partial) {
    __shared__ int s[256];
    int i = blockIdx.x * 256 + threadIdx.x;
    s[threadIdx.x] = (i < NTOT) ? cnt[i] : 0;
    __syncthreads();
    for (int off = 128; off > 0; off >>= 1) {
        if (threadIdx.x < off) s[threadIdx.x] += s[threadIdx.x + off];
        __syncthreads();
    }
    if (threadIdx.x == 0) partial[blockIdx.x] = s[0];
}

__global__ void k_scan_b(int* __restrict__ partial, int nblk) {
    __shared__ int s[512];
    int t = threadIdx.x;
    s[t] = (t < nblk) ? partial[t] : 0;
    __syncthreads();
    for (int off = 1; off < 512; off <<= 1) {
        int v = (t >= off) ? s[t - off] : 0;
        __syncthreads();
        s[t] += v;
        __syncthreads();
    }
    if (t < nblk) partial[t] = t ? s[t - 1] : 0;   // exclusive
}

__global__ void k_scan_c(const int* __restrict__ cnt, const int* __restrict__ partial,
                         int* __restrict__ row_ptr) {
    __shared__ int s[256];
    int i = blockIdx.x * 256 + threadIdx.x, t = threadIdx.x;
    int v = (i < NTOT) ? cnt[i] : 0;
    s[t] = v;
    __syncthreads();
    for (int off = 1; off < 256; off <<= 1) {
        int u = (t >= off) ? s[t - off] : 0;
        __syncthreads();
        s[t] += u;
        __syncthreads();
    }
    if (i < NTOT) row_ptr[i] = s[t] - v + partial[blockIdx.x];
    if (i == NTOT - 1) row_ptr[NTOT] = s[t] + partial[blockIdx.x];
}

__global__ void k_fill(EdgePtrs ep, const int* __restrict__ row_ptr,
                       int* __restrict__ cursor, int* __restrict__ csr) {
    int eidx = blockIdx.x * blockDim.x + threadIdx.x;
    if (eidx >= ETOT) return;
    int e = 0;
    #pragma unroll
    for (int i = 1; i < 13; i++) e += (eidx >= d_EOFF[i]);
    int li = eidx - d_EOFF[e];
    const int* base = ep.p[e];
    int src = base[li], dst = base[d_ECNT[e] + li];
    int dg = d_NOFF[d_EDT[e]] + dst;
    int pos = atomicAdd(&cursor[dg], 1);
    csr[row_ptr[dg] + pos] = d_EBASE[e] + src;
}

// ---------------- kqv: q -> fp32; k,v -> half tables (16-node tiles) ----------------
__global__ __launch_bounds__(192)
void k_kqv(const float* __restrict__ h, const float* __restrict__ Wkqv,
           const float* __restrict__ bkqv, float* __restrict__ qagg,
           __half* __restrict__ ktab, __half* __restrict__ vtab, int layer) {
    int n0 = blockIdx.x * 16;
    if (n0 >= NTOT) return;
    int t = node_type(n0);          // 16-node tiles never straddle type boundaries
    int nn = min(16, NTOT - n0);
    __shared__ float hs[16][64];
    for (int i = threadIdx.x; i < nn * 64; i += 192)
        hs[i >> 6][i & 63] = h[(size_t)n0 * 64 + i];
    __syncthreads();
    const float* W = Wkqv + (size_t)(layer * 3 + t) * HID * 192;
    int j = threadIdx.x;
    float b = bkqv[(layer * 3 + t) * 192 + j];
    float acc[16];
    #pragma unroll
    for (int n = 0; n < 16; n++) acc[n] = b;
    for (int i = 0; i < 64; i++) {
        float w = W[i * 192 + j];
        #pragma unroll
        for (int n = 0; n < 16; n++) acc[n] += hs[n][i] * w;
    }
    if (j < 64) {
        for (int n = 0; n < nn; n++) ktab[(size_t)(n0 + n) * 64 + j] = __float2half(acc[n]);
    } else if (j < 128) {
        for (int n = 0; n < nn; n++) qagg[(size_t)(n0 + n) * 64 + (j - 64)] = acc[n];
    } else {
        for (int n = 0; n < nn; n++) vtab[(size_t)(n0 + n) * 64 + (j - 128)] = __float2half(acc[n]);
    }
}

// ---- trans: kvt[slot][h*16+x] = half2( prel*scale*sum_d k[h,d]Wk[e,h,d,x],
//                                        sum_d v[h,d]Wv[e,h,d,x] )
__global__ __launch_bounds__(512)
void k_trans(const __half* __restrict__ ktab, const __half* __restrict__ vtab,
             const float* __restrict__ Wk, const float* __restrict__ Wv,
             const float* __restrict__ prel, __half2* __restrict__ kvt, int layer) {
    int b = blockIdx.x;
    int e = 0;
    #pragma unroll
    for (int i = 1; i < 13; i++) e += (b >= d_TBOFF[i]);
    int s0 = d_EBASE[e] + (b - d_TBOFF[e]) * 64;
    int lim = d_EBASE[e] + d_ESLOTS[e];
    int wave = threadIdx.x >> 6, lane = threadIdx.x & 63;
    int h = lane >> 4, xo = lane & 15;
    const float* Wkp = Wk + (((size_t)layer * 13 + e) * 4 + h) * 256 + xo;
    const float* Wvp = Wv + (((size_t)layer * 13 + e) * 4 + h) * 256 + xo;
    float pr = prel[(layer * 13 + e) * 4 + h] * 0.25f;
    float wk[16], wv[16];
    #pragma unroll
    for (int d = 0; d < 16; d++) { wk[d] = Wkp[d * 16] * pr; wv[d] = Wvp[d * 16]; }
    int nbase = d_NOFF[d_EST[e]] - d_EBASE[e];
    for (int k = 0; k < 8; k++) {
        int slot = s0 + wave * 8 + k;
        if (slot >= lim) break;                     // uniform across wave
        const float4* kp4 = (const float4*)(ktab + (size_t)(nbase + slot) * 64 + h * 16);
        const float4* vp4 = (const float4*)(vtab + (size_t)(nbase + slot) * 64 + h * 16);
        float4 k0 = kp4[0], k1 = kp4[1];            // 16 halfs in 2 loads
        float4 v0 = vp4[0], v1 = vp4[1];
        const __half2* kh0 = (const __half2*)&k0;
        const __half2* kh1 = (const __half2*)&k1;
        const __half2* vh0 = (const __half2*)&v0;
        const __half2* vh1 = (const __half2*)&v1;
        float kt = 0.f, vt = 0.f;
        #pragma unroll
        for (int d2 = 0; d2 < 4; d2++) {
            float2 kf = __half22float2(kh0[d2]);
            float2 vf = __half22float2(vh0[d2]);
            kt += kf.x * wk[2 * d2] + kf.y * wk[2 * d2 + 1];
            vt += vf.x * wv[2 * d2] + vf.y * wv[2 * d2 + 1];
        }
        #pragma unroll
        for (int d2 = 0; d2 < 4; d2++) {
            float2 kf = __half22float2(kh1[d2]);
            float2 vf = __half22float2(vh1[d2]);
            kt += kf.x * wk[8 + 2 * d2] + kf.y * wk[8 + 2 * d2 + 1];
            vt += vf.x * wv[8 + 2 * d2] + vf.y * wv[8 + 2 * d2 + 1];
        }
        kvt[(size_t)slot * 64 + lane] = __float22half2_rn(make_float2(kt, vt));
    }
}

// ---------------- fused gather: score + online softmax + message agg ----------------
__global__ __launch_bounds__(512)
void k_gather(float* __restrict__ qagg, const __half2* __restrict__ kvt,
              const int* __restrict__ row_ptr, const int* __restrict__ csr) {
    int wave = threadIdx.x >> 6, lane = threadIdx.x & 63;
    int node = blockIdx.x * 8 + wave;
    if (node >= NTOT) return;
    float q = qagg[(size_t)node * 64 + lane];   // q[h][x]
    int beg = row_ptr[node], end = row_ptr[node + 1];
    float m0 = -1e30f, l0 = 0.f, a0 = 0.f;      // dual softmax accumulators
    float m1 = -1e30f, l1 = 0.f, a1 = 0.f;      // (even/odd edges, merged at end)
    for (int base = beg; base < end; base += 64) {
        int n = end - base; if (n > 64) n = 64;
        int ent = csr[base + ((lane < n) ? lane : 0)];   // 64 entries in one load
        for (int c = 0; c < n; c += 16) {
            int cn = n - c; if (cn > 16) cn = 16;
            __half2 f[16];
            #pragma unroll
            for (int k = 0; k < 16; k++) {               // masked batch of gathers
                if (k < cn) {                            // wave-uniform branch
                    int sl = __shfl(ent, c + k, 64);
                    f[k] = kvt[(size_t)sl * 64 + lane];
                }
            }
            #pragma unroll
            for (int k = 0; k < 16; k += 2) {
                if (k >= cn) break;
                {
                    float2 kv2 = __half22float2(f[k]);
                    float s = q * kv2.x;
                    s += __shfl_xor(s, 1, 64); s += __shfl_xor(s, 2, 64);
                    s += __shfl_xor(s, 4, 64); s += __shfl_xor(s, 8, 64);
                    float d = s - m0;
                    float t = __expf(-fabsf(d));
                    bool pos = d > 0.f;
                    m0 = fmaxf(m0, s);
                    float sc = pos ? t : 1.f, es = pos ? 1.f : t;
                    l0 = l0 * sc + es;
                    a0 = a0 * sc + es * kv2.y;
                }
                if (k + 1 < cn) {
                    float2 kv2 = __half22float2(f[k + 1]);
                    float s = q * kv2.x;
                    s += __shfl_xor(s, 1, 64); s += __shfl_xor(s, 2, 64);
                    s += __shfl_xor(s, 4, 64); s += __shfl_xor(s, 8, 64);
                    float d = s - m1;
                    float t = __expf(-fabsf(d));
                    bool pos = d > 0.f;
                    m1 = fmaxf(m1, s);
                    float sc = pos ? t : 1.f, es = pos ? 1.f : t;
                    l1 = l1 * sc + es;
                    a1 = a1 * sc + es * kv2.y;
                }
            }
        }
    }
    float M  = fmaxf(m0, m1);
    float e0 = __expf(m0 - M), e1 = __expf(m1 - M);
    float l  = l0 * e0 + l1 * e1;
    float acc = a0 * e0 + a1 * e1;
    qagg[(size_t)node * 64 + lane] = (l > 0.f) ? acc / l : 0.f;
}

// ---------------- epilogue: gelu -> @Wout + bout -> skip-gate -> relu ----------------
__global__ __launch_bounds__(256)
void k_out(const float* __restrict__ agg, const float* __restrict__ Wout,
           const float* __restrict__ bout, const float* __restrict__ skip,
           float* __restrict__ h, int layer) {
    int b = blockIdx.x; int t, n0, lim;
    if (b < 938)       { t = 0; n0 = b * 32;                 lim = NU; }
    else if (b < 2813) { t = 1; n0 = NU + (b - 938) * 32;    lim = NU + NE_; }
    else               { t = 2; n0 = NU + NE_ + (b - 2813) * 32; lim = NTOT; }
    int nn = min(32, lim - n0);
    __shared__ float gs[32][64];
    for (int i = threadIdx.x; i < nn * 64; i += 256) {
        float o = agg[(size_t)n0 * 64 + i];
        gs[i >> 6][i & 63] = 0.5f * o * (1.f + erff(o * 0.70710678118654752f));
    }
    __syncthreads();
    int j = threadIdx.x & 63, g = threadIdx.x >> 6;   // 4 groups x 8 nodes
    const float* W = Wout + (size_t)(layer * 3 + t) * HID * HID;
    float bb = bout[(layer * 3 + t) * HID + j];
    float acc[8];
    #pragma unroll
    for (int n = 0; n < 8; n++) acc[n] = bb;
    for (int i = 0; i < 64; i++) {
        float w = W[i * 64 + j];
        #pragma unroll
        for (int n = 0; n < 8; n++) acc[n] += gs[g * 8 + n][i] * w;
    }
    float gk = 1.f / (1.f + __expf(-skip[layer * 3 + t]));
    #pragma unroll
    for (int n = 0; n < 8; n++) {
        int node = n0 + g * 8 + n;
        if (node < lim) {
            float r = gk * acc[n] + (1.f - gk) * h[(size_t)node * 64 + j];
            h[(size_t)node * 64 + j] = fmaxf(r, 0.f);
        }
    }
}

// ---------------- final l2 normalize ----------------
__global__ void k_l2(const float* __restrict__ h, float* __restrict__ out) {
    int node = blockIdx.x, j = threadIdx.x;   // 64 = one wave
    float v = h[(size_t)node * HID + j];
    float ss = v * v;
    #pragma unroll
    for (int off = 32; off > 0; off >>= 1) ss += __shfl_down(ss, off);
    ss = __shfl(ss, 0);
    float nrm = fmaxf(sqrtf(ss), 1e-12f);
    out[(size_t)node * HID + j] = v / nrm;
}

extern "C" void kernel_launch(void* const* d_in, const int* in_sizes, int n_in,
                              void* d_out, int out_size, void* d_ws, size_t ws_size,
                              hipStream_t stream) {
    const float* xu   = (const float*)d_in[0];
    const float* xe   = (const float*)d_in[1];
    const float* xv   = (const float*)d_in[2];
    const float* Wu   = (const float*)d_in[3];
    const float* bu   = (const float*)d_in[4];
    const float* We   = (const float*)d_in[5];
    const float* be   = (const float*)d_in[6];
    const float* Wv_  = (const float*)d_in[7];
    const float* bv   = (const float*)d_in[8];
    const float* embu = (const float*)d_in[9];
    const float* embe = (const float*)d_in[10];
    const float* embv = (const float*)d_in[11];
    const float* Wkqv = (const float*)d_in[12];
    const float* bkqv = (const float*)d_in[13];
    const float* Wk   = (const float*)d_in[14];
    const float* Wv   = (const float*)d_in[15];
    const float* prel = (const float*)d_in[16];
    const float* Wout = (const float*)d_in[17];
    const float* bout = (const float*)d_in[18];
    const float* skip = (const float*)d_in[19];
    const int*   idu  = (const int*)d_in[20];
    const int*   ide  = (const int*)d_in[21];
    const int*   idv  = (const int*)d_in[22];
    EdgePtrs ep;
    for (int e = 0; e < 13; e++) ep.p[e] = (const int*)d_in[23 + e];

    float* ws  = (float*)d_ws;
    float* h      = ws;                                    // NTOT*64 f32
    float* qagg   = h    + (size_t)NTOT * HID;             // NTOT*64 f32 (q, then agg)
    __half* ktab  = (__half*)(qagg + (size_t)NTOT * HID);  // NTOT*64 half
    __half* vtab  = ktab + (size_t)NTOT * HID;             // NTOT*64 half
    __half2* kvt  = (__half2*)(vtab + (size_t)NTOT * HID); // NSLOT*64 half2
    int* cnt     = (int*)(kvt + (size_t)NSLOT * HID);      // NTOT
    int* cursor  = cnt + NTOT;                             // NTOT
    int* row_ptr = cursor + NTOT;                          // NTOT+1
    int* partial = row_ptr + NTOT + 1;                     // 512
    int* csr     = partial + 512;                          // ETOT int

    k_init<<<(NTOT * HID + 255) / 256, 256, 0, stream>>>(
        xu, xe, xv, Wu, bu, We, be, Wv_, bv, embu, embe, embv, idu, ide, idv, h);

    // CSR build (edges are layer-invariant); exact rows, entry = slot id
    hipMemsetAsync(cnt, 0, (size_t)2 * NTOT * 4, stream);   // cnt + cursor
    int nblk = (NTOT + 255) / 256;   // 356
    k_cnt<<<(ETOT + 255) / 256, 256, 0, stream>>>(ep, cnt);
    k_scan_a<<<nblk, 256, 0, stream>>>(cnt, partial);
    k_scan_b<<<1, 512, 0, stream>>>(partial, nblk);
    k_scan_c<<<nblk, 256, 0, stream>>>(cnt, partial, row_ptr);
    k_fill<<<(ETOT + 255) / 256, 256, 0, stream>>>(ep, row_ptr, cursor, csr);

    for (int l = 0; l < LAYERS; l++) {
        k_kqv<<<(NTOT + 15) / 16, 192, 0, stream>>>(h, Wkqv, bkqv, qagg, ktab, vtab, l);
        k_trans<<<8458, 512, 0, stream>>>(ktab, vtab, Wk, Wv, prel, kvt, l);
        k_gather<<<(NTOT + 7) / 8, 512, 0, stream>>>(qagg, kvt, row_ptr, csr);
        k_out<<<2845, 256, 0, stream>>>(qagg, Wout, bout, skip, h, l);
    }
    k_l2<<<NTOT, HID, 0, stream>>>(h, (float*)d_out);
}